// Round 1
// baseline (1028.559 us; speedup 1.0000x reference)
//
#include <hip/hip_runtime.h>
#include <hip/hip_bf16.h>
#include <cstdint>
#include <cstddef>

#define TOKENS   32768
#define DDIM     4096
#define NEXP     64
#define N2       65536       // TOKENS*2 slots
#define CAPACITY 1126        // int(32768*1.1*2/64)

// ---------------- workspace byte offsets ----------------
// Wt      : float[4096*64]  (transposed router weight)      @ 0        (1 MiB)
// p_flat  : float[N2]       (renormalized top-2 probs)      @ 1 MiB    (256 KiB)
// e_flat  : int[N2]         (expert id per slot)            @ +256 KiB (256 KiB)
// psum    : float[64]       (per-expert prob column sums)   @ +512 KiB
// counts  : int[64]         (pre-truncation per-expert cnt) @ +512 KiB + 256 B
#define WS_WT    0
#define WS_PFLAT (1u << 20)
#define WS_EFLAT ((1u << 20) + 262144u)
#define WS_PSUM  ((1u << 20) + 524288u)
#define WS_CNT   ((1u << 20) + 524288u + 256u)

// ---------------- zero dispatch+combine and psum ----------------
__global__ void zero_kernel(float* __restrict__ dc, float* __restrict__ psum) {
    int idx = blockIdx.x * blockDim.x + threadIdx.x;
    float4 z = make_float4(0.f, 0.f, 0.f, 0.f);
    const int n4 = (2 * TOKENS * NEXP) / 4;   // dispatch+combine are contiguous
    for (int i = idx; i < n4; i += gridDim.x * blockDim.x)
        ((float4*)dc)[i] = z;
    if (idx < NEXP) psum[idx] = 0.f;
}

// ---------------- W[e][d] -> Wt[d][e] ----------------
__global__ void transpose_w(const float* __restrict__ W, float* __restrict__ Wt) {
    int idx = blockIdx.x * 256 + threadIdx.x;   // 262144 total
    int d = idx >> 6, e = idx & 63;
    Wt[idx] = W[(size_t)e * DDIM + d];
}

// ---------------- fused router: GEMM + softmax + top2 ----------------
// 512 blocks x 256 threads; block handles 64 tokens x 64 experts, D chunked by 64.
__launch_bounds__(256, 2)
__global__ void router_kernel(const float* __restrict__ x, const float* __restrict__ Wt,
                              float* __restrict__ probs_out, float* __restrict__ p_flat,
                              int* __restrict__ e_flat, float* __restrict__ psum) {
    __shared__ __align__(16) float xs[64][68];   // [tok][kk]
    __shared__ __align__(16) float wt[64][68];   // [kk][e]
    __shared__ __align__(16) float prow[64][68]; // logits -> probs, [tok][e]
    __shared__ float red[256];

    const int tid  = threadIdx.x;
    const int tok0 = blockIdx.x * 64;
    const int ty4  = (tid >> 4) * 4;   // token group base (0..60)
    const int tx4  = (tid & 15) * 4;   // expert group base (0..60)

    float tacc[4][4];
#pragma unroll
    for (int i = 0; i < 4; ++i)
#pragma unroll
        for (int j = 0; j < 4; ++j) tacc[i][j] = 0.f;

    for (int d0 = 0; d0 < DDIM; d0 += 64) {
        __syncthreads();   // previous chunk's LDS reads done
#pragma unroll
        for (int it = 0; it < 4; ++it) {
            int q   = it * 256 + tid;
            int row = q >> 4;          // token idx / Wt-row idx (0..63)
            int fp  = (q & 15) * 4;    // float position within 64-wide row
            float4 xv = *(const float4*)&x[(size_t)(tok0 + row) * DDIM + d0 + fp];
            *(float4*)&xs[row][fp] = xv;
            float4 wv = *(const float4*)&Wt[(size_t)(d0 + row) * 64 + fp];
            *(float4*)&wt[row][fp] = wv;
        }
        __syncthreads();

        float cacc[4][4];
#pragma unroll
        for (int i = 0; i < 4; ++i)
#pragma unroll
            for (int j = 0; j < 4; ++j) cacc[i][j] = 0.f;

#pragma unroll 4
        for (int kk = 0; kk < 64; kk += 4) {
            float xr[4][4], wr[4][4];
#pragma unroll
            for (int i = 0; i < 4; ++i)
                *(float4*)xr[i] = *(const float4*)&xs[ty4 + i][kk];
#pragma unroll
            for (int t = 0; t < 4; ++t)
                *(float4*)wr[t] = *(const float4*)&wt[kk + t][tx4];
#pragma unroll
            for (int i = 0; i < 4; ++i)
#pragma unroll
                for (int t = 0; t < 4; ++t)
#pragma unroll
                    for (int j = 0; j < 4; ++j)
                        cacc[i][j] = fmaf(xr[i][t], wr[t][j], cacc[i][j]);
        }
#pragma unroll
        for (int i = 0; i < 4; ++i)
#pragma unroll
            for (int j = 0; j < 4; ++j) tacc[i][j] += cacc[i][j];
    }

    __syncthreads();
    // stash logits: prow[tok][e]
#pragma unroll
    for (int i = 0; i < 4; ++i)
        *(float4*)&prow[ty4 + i][tx4] =
            make_float4(tacc[i][0], tacc[i][1], tacc[i][2], tacc[i][3]);
    __syncthreads();

    if (tid < 64) {
        const int t = tid;
        float m = -INFINITY;
        for (int e = 0; e < 64; ++e) m = fmaxf(m, prow[t][e]);
        float s = 0.f;
        for (int e = 0; e < 64; ++e) {
            float v = expf(prow[t][e] - m);
            prow[t][e] = v;
            s += v;
        }
        // divide then top-2 on the divided values (matches np top_k on probs,
        // stable lower-index-first tie-breaking)
        float p1 = -1.f, p2 = -1.f; int i1 = 0, i2 = 0;
        for (int e = 0; e < 64; ++e) {
            float p = prow[t][e] / s;
            prow[t][e] = p;
            if (p > p1)      { p2 = p1; i2 = i1; p1 = p; i1 = e; }
            else if (p > p2) { p2 = p;  i2 = e; }
        }
        float rs  = p1 + p2;
        float pn1 = p1 / rs, pn2 = p2 / rs;
        int g = tok0 + t;
        p_flat[2 * g]     = pn1;
        p_flat[2 * g + 1] = pn2;
        e_flat[2 * g]     = i1;
        e_flat[2 * g + 1] = i2;
    }
    __syncthreads();

    // coalesced probs write + per-expert column partial sums
    float acc = 0.f;
#pragma unroll
    for (int k = 0; k < 16; ++k) {
        int idx = k * 256 + tid;
        int tok = idx >> 6, e = idx & 63;
        float p = prow[tok][e];
        probs_out[(size_t)(tok0 + tok) * 64 + e] = p;
        acc += p;
    }
    red[tid] = acc;
    __syncthreads();
    if (tid < 64) {
        float v = red[tid] + red[tid + 64] + red[tid + 128] + red[tid + 192];
        atomicAdd(&psum[tid], v);
    }
}

// ---------------- per-expert capacity ranking + scatter ----------------
// 64 blocks (one per expert) x 256 threads. Bitonic sort of packed keys:
// key = (float_bits(prob) << 32) | (0xFFFFFFFF - slot)  -> descending sort
// reproduces stable argsort by (-prob, slot).
__launch_bounds__(256, 2)
__global__ void expert_sort_kernel(const float* __restrict__ p_flat,
                                   const int* __restrict__ e_flat,
                                   float* __restrict__ dispatch,
                                   float* __restrict__ combine,
                                   int* __restrict__ counts) {
    __shared__ unsigned long long keys[4096];
    __shared__ int cnt;
    const int tid = threadIdx.x;
    const int e   = blockIdx.x;

    if (tid == 0) cnt = 0;
    __syncthreads();

    for (int slot = tid; slot < N2; slot += 256) {
        if (e_flat[slot] == e) {
            float p = p_flat[slot];
            int pos = atomicAdd(&cnt, 1);
            if (pos < 4096)
                keys[pos] = ((unsigned long long)__float_as_uint(p) << 32) |
                            (unsigned long long)(0xFFFFFFFFu - (unsigned)slot);
        }
    }
    __syncthreads();
    const int n = cnt;
    for (int i = tid; i < 4096; i += 256)
        if (i >= n) keys[i] = 0ull;   // pads sort last (prob bits 0, low32 0)
    __syncthreads();

    // bitonic sort, descending
    for (int k = 2; k <= 4096; k <<= 1) {
        for (int j = k >> 1; j > 0; j >>= 1) {
#pragma unroll
            for (int w = 0; w < 16; ++w) {
                int i   = w * 256 + tid;
                int ixj = i ^ j;
                if (ixj > i) {
                    bool desc = ((i & k) == 0);
                    unsigned long long a = keys[i], b = keys[ixj];
                    bool sw = desc ? (a < b) : (a > b);
                    if (sw) { keys[i] = b; keys[ixj] = a; }
                }
            }
            __syncthreads();
        }
    }

    int lim = n < CAPACITY ? n : CAPACITY;
    for (int pos = tid; pos < lim; pos += 256) {
        unsigned long long key = keys[pos];
        unsigned slot = 0xFFFFFFFFu - (unsigned)(key & 0xFFFFFFFFull);
        float p = __uint_as_float((unsigned)(key >> 32));
        int token = (int)(slot >> 1);
        dispatch[(size_t)token * 64 + e] = 1.0f;
        combine [(size_t)token * 64 + e] = p;
    }
    if (tid == 0) counts[e] = n;
}

// ---------------- aux loss ----------------
__global__ void aux_kernel(const float* __restrict__ psum,
                           const int* __restrict__ counts,
                           float* __restrict__ out_aux) {
    int tid = threadIdx.x;   // 64 threads
    float v = (psum[tid] / (float)TOKENS) * ((float)counts[tid] / (float)N2);
    for (int off = 32; off > 0; off >>= 1) v += __shfl_down(v, off, 64);
    if (tid == 0) *out_aux = v * (float)NEXP;
}

extern "C" void kernel_launch(void* const* d_in, const int* in_sizes, int n_in,
                              void* d_out, int out_size, void* d_ws, size_t ws_size,
                              hipStream_t stream) {
    (void)in_sizes; (void)n_in; (void)out_size; (void)ws_size;

    const float* x = (const float*)d_in[0];
    const float* W = (const float*)d_in[1];

    float* out      = (float*)d_out;
    float* dispatch = out;                         // [32768*64]
    float* combine  = out + (size_t)TOKENS * NEXP; // [32768*64]
    float* probs    = out + (size_t)2 * TOKENS * NEXP;
    float* aux      = out + (size_t)3 * TOKENS * NEXP;

    char*  ws     = (char*)d_ws;
    float* Wt     = (float*)(ws + WS_WT);
    float* p_flat = (float*)(ws + WS_PFLAT);
    int*   e_flat = (int*)  (ws + WS_EFLAT);
    float* psum   = (float*)(ws + WS_PSUM);
    int*   counts = (int*)  (ws + WS_CNT);

    zero_kernel<<<1024, 256, 0, stream>>>(dispatch, psum);
    transpose_w<<<1024, 256, 0, stream>>>(W, Wt);
    router_kernel<<<512, 256, 0, stream>>>(x, Wt, probs, p_flat, e_flat, psum);
    expert_sort_kernel<<<64, 256, 0, stream>>>(p_flat, e_flat, dispatch, combine, counts);
    aux_kernel<<<1, 64, 0, stream>>>(psum, counts, aux);
}